// Round 5
// baseline (168.287 us; speedup 1.0000x reference)
//
#include <hip/hip_runtime.h>
#include <hip/hip_fp16.h>

#define NW 18
#define NSTATE (1u << NW)                      // 262144 per batch
#define NBATCH 32
#define TOTAL (NBATCH * (size_t)NSTATE)        // 8388608 elements

typedef float v2f __attribute__((ext_vector_type(2)));
typedef _Float16 h2v __attribute__((ext_vector_type(2)));

struct Masks { unsigned m[18]; };

// ---- packed complex arithmetic via VOP3P op_sel/neg folding -------------------
__device__ __forceinline__ v2f pk_mulsw(v2f g, v2f b) {   // (-g.im*b.im, g.im*b.re)
    v2f d;
    asm("v_pk_mul_f32 %0, %1, %2 op_sel:[1,1] op_sel_hi:[1,0] neg_lo:[1,0]"
        : "=v"(d) : "v"(g), "v"(b));
    return d;
}
__device__ __forceinline__ v2f pk_fmare(v2f g, v2f a, v2f c) { // (g.re*a.re+c.x, g.re*a.im+c.y)
    v2f d;
    asm("v_pk_fma_f32 %0, %1, %2, %3 op_sel:[0,0,0] op_sel_hi:[0,1,1]"
        : "=v"(d) : "v"(g), "v"(a), "v"(c));
    return d;
}
__device__ __forceinline__ v2f pk_fmasw(v2f g, v2f a, v2f c) { // (-g.im*a.im+c.x, g.im*a.re+c.y)
    v2f d;
    asm("v_pk_fma_f32 %0, %1, %2, %3 op_sel:[1,1,0] op_sel_hi:[1,0,1] neg_lo:[1,0,0]"
        : "=v"(d) : "v"(g), "v"(a), "v"(c));
    return d;
}
__device__ __forceinline__ v2f cmul(v2f g, v2f x) { return pk_fmare(g, x, pk_mulsw(g, x)); }
__device__ __forceinline__ v2f cmad(v2f g, v2f x, v2f c) { return pk_fmare(g, x, pk_fmasw(g, x, c)); }

__device__ __forceinline__ void bfly(v2f& a, v2f& b, v2f g00, v2f g01, v2f g10, v2f g11) {
    v2f na = cmad(g00, a, cmul(g01, b));
    v2f nb = cmad(g10, a, cmul(g11, b));
    a = na; b = nb;
}

__device__ __forceinline__ unsigned pack(v2f v) {
    return __builtin_bit_cast(unsigned, __builtin_amdgcn_cvt_pkrtz(v.x, v.y));
}
__device__ __forceinline__ v2f unpack(unsigned u) {
    h2v h = __builtin_bit_cast(h2v, u);
    return (v2f){(float)h.x, (float)h.y};
}

__device__ __forceinline__ int swz(int n) { return n ^ ((n >> 5) & 31); }

__device__ __forceinline__ constexpr int ctzc(int x) {
    int c = 0; while (!(x & 1)) { x >>= 1; c++; } return c;
}

#define GATES(gb)                                                      \
    const float4 G0_ = Ut[(17-(gb))*2+0], G1_ = Ut[(17-(gb))*2+1];     \
    const v2f g00 = {G0_.x, G0_.y}, g01 = {G0_.z, G0_.w};              \
    const v2f g10 = {G1_.x, G1_.y}, g11 = {G1_.z, G1_.w};

// ---- Rot gate matrix from (phi, theta, omega) ---------------------------------
__device__ __forceinline__ void make_gate(const float* __restrict__ p,
                                          float4& G0, float4& G1) {
    float phi = p[0], th = p[1], om = p[2];
    float ch = cosf(th*0.5f), sh = sinf(th*0.5f);
    float a0 = -0.5f*(phi+om), a1 = 0.5f*(phi-om);
    float c0 = cosf(a0), s0 = sinf(a0);
    float c1 = cosf(a1), s1 = sinf(a1);
    G0 = make_float4(c0*ch,  s0*ch, -c1*sh, -s1*sh);
    G1 = make_float4(c1*sh, -s1*sh,  c0*ch, -s0*ch);
}

// ---- pass A: butterflies on bits 0..11 within contiguous 4096 blocks ----------
// 256 threads x 16 elems; 3 register phases of 4 bits, 2 LDS exchanges.
// FIRST=1: src is f32 x; also computes all 36 gates (block 0 -> global Utab),
// accumulates per-block sum-of-squares into partials. State stays UNSCALED.
template<int FIRST>
__global__ __launch_bounds__(256, 8) void passA(const void* __restrict__ src,
                                                unsigned* __restrict__ dst,
                                                float4* __restrict__ Utab,
                                                float* __restrict__ partials,
                                                const float* __restrict__ params,
                                                int layer) {
    __shared__ unsigned sm[4096];   // 16 KB
    __shared__ float4 gl[72];       // 36 gates x 2
    __shared__ float wsum[4];
    const int t = threadIdx.x;      // 0..255
    const size_t base = (size_t)blockIdx.x * 4096;
    v2f v[16];
    const float4* Ut;
    float ss = 0.f;

    if (FIRST) {
        const float4* xs = (const float4*)((const float*)src + base + (size_t)t * 16);
        float4 q[4];
#pragma unroll
        for (int j = 0; j < 4; j++) q[j] = xs[j];

        if (t < 36) {                       // both layers' gates, redundantly per block
            float4 G0, G1;
            make_gate(params + t*3, G0, G1);
            gl[t*2] = G0; gl[t*2+1] = G1;
            if (blockIdx.x == 0) { Utab[t*2] = G0; Utab[t*2+1] = G1; }
        }

#pragma unroll
        for (int j = 0; j < 4; j++) {
            v[j*4+0] = (v2f){q[j].x, 0.f};
            v[j*4+1] = (v2f){q[j].y, 0.f};
            v[j*4+2] = (v2f){q[j].z, 0.f};
            v[j*4+3] = (v2f){q[j].w, 0.f};
            ss += q[j].x*q[j].x + q[j].y*q[j].y + q[j].z*q[j].z + q[j].w*q[j].w;
        }
#pragma unroll
        for (int m = 32; m >= 1; m >>= 1) ss += __shfl_xor(ss, m, 64);
        if ((t & 63) == 0) wsum[t >> 6] = ss;
        __syncthreads();                    // gates (and wsum) visible
        Ut = gl;                            // layer 0 lives at gl[0..35]
    } else {
        const uint4* xs = (const uint4*)((const unsigned*)src + base + (size_t)t * 16);
#pragma unroll
        for (int j = 0; j < 4; j++) {
            uint4 q = xs[j];
            v[j*4+0] = unpack(q.x);
            v[j*4+1] = unpack(q.y);
            v[j*4+2] = unpack(q.z);
            v[j*4+3] = unpack(q.w);
        }
        Ut = (const float4*)Utab + (size_t)layer * 36;
    }

    // phase 1: bits 0..3 (element k = n&15)
#pragma unroll
    for (int b = 0; b < 4; b++) {
        GATES(b);
#pragma unroll
        for (int k = 0; k < 16; k++)
            if (!(k & (1 << b))) bfly(v[k], v[k | (1 << b)], g00, g01, g10, g11);
    }

    // exchange 1: L1 n = (t<<4)|k  ->  L2 n = (t&15) | k<<4 | (t>>4)<<8
#pragma unroll
    for (int k = 0; k < 16; k++)
        sm[swz((t << 4) | k)] = pack(v[k]);
    __syncthreads();
    if (FIRST && t == 0)
        partials[blockIdx.x] = wsum[0] + wsum[1] + wsum[2] + wsum[3];
#pragma unroll
    for (int k = 0; k < 16; k++)
        v[k] = unpack(sm[swz((t & 15) | (k << 4) | ((t >> 4) << 8))]);

    // phase 2: bits 4..7 (element k = (n>>4)&15)
#pragma unroll
    for (int b = 4; b < 8; b++) {
        GATES(b);
        const int pb = 1 << (b - 4);
#pragma unroll
        for (int k = 0; k < 16; k++)
            if (!(k & pb)) bfly(v[k], v[k | pb], g00, g01, g10, g11);
    }

    // exchange 2: write back own L2 slots (disjoint, no pre-sync), read L3
#pragma unroll
    for (int k = 0; k < 16; k++)
        sm[swz((t & 15) | (k << 4) | ((t >> 4) << 8))] = pack(v[k]);
    __syncthreads();
#pragma unroll
    for (int k = 0; k < 16; k++)
        v[k] = unpack(sm[swz(t | (k << 8))]);

    // phase 3: bits 8..11 (element k = (n>>8)&15)
#pragma unroll
    for (int b = 8; b < 12; b++) {
        GATES(b);
        const int pb = 1 << (b - 8);
#pragma unroll
        for (int k = 0; k < 16; k++)
            if (!(k & pb)) bfly(v[k], v[k | pb], g00, g01, g10, g11);
    }

    // store (L3 layout: lane-contiguous, coalesced)
#pragma unroll
    for (int k = 0; k < 16; k++)
        dst[base + (t | (k << 8))] = pack(v[k]);
}

// ---- pass B: butterflies on bits 12..17, then CNOT-chain scatter --------------
// 256 threads x 16 elems. Block = 64 contiguous lows x all 64 highs (bits 12..17).
// LAST=1: write sc*|amp| as f32 to out; else packed fp16x2 state.
template<int LAST>
__global__ __launch_bounds__(256, 8) void passB(const unsigned* __restrict__ src,
                                                void* __restrict__ dst,
                                                const float4* __restrict__ Utab,
                                                const float* __restrict__ partials,
                                                int layer, Masks mk) {
    __shared__ unsigned sm[4096];   // 16 KB
    const int t = threadIdx.x;                 // 0..255
    const unsigned blk = blockIdx.x;           // 2048 blocks
    const unsigned batch = blk >> 6;
    const unsigned chunk = blk & 63;
    const unsigned low = chunk * 64 + (t & 63);   // 12-bit low index
    const unsigned j = t >> 6;                 // 0..3 (wave id)
    const size_t bb = (size_t)batch << NW;

    v2f v[16];
    // phase-1 ownership: h = (j<<4)|k  (k = h bits 0..3 = state bits 12..15)
#pragma unroll
    for (int k = 0; k < 16; k++) {
        unsigned h = (j << 4) | k;
        v[k] = unpack(src[bb + ((size_t)h << 12) + low]);
    }

    const float4* Ut = Utab + (size_t)layer * 36;
#pragma unroll
    for (int b = 12; b < 16; b++) {
        GATES(b);
        const int pb = 1 << (b - 12);
#pragma unroll
        for (int k = 0; k < 16; k++)
            if (!(k & pb)) bfly(v[k], v[k | pb], g00, g01, g10, g11);
    }

    // exchange: slot n = (h<<6) | (t&63); lanes consecutive -> conflict-free
#pragma unroll
    for (int k = 0; k < 16; k++) {
        unsigned h = (j << 4) | k;
        sm[(h << 6) | (t & 63)] = pack(v[k]);
    }
    __syncthreads();
    // phase-2 ownership: h = (q<<4) | (j<<2) | r, element idx = (q<<2)|r
#pragma unroll
    for (int q = 0; q < 4; q++)
#pragma unroll
        for (int r = 0; r < 4; r++) {
            unsigned h = (q << 4) | (j << 2) | r;
            v[(q << 2) | r] = unpack(sm[(h << 6) | (t & 63)]);
        }

    // bit 16 (wire 1): pairs idx, idx^4 ; bit 17 (wire 0): pairs idx, idx^8
    {
        GATES(16);
#pragma unroll
        for (int k = 0; k < 16; k++)
            if (!(k & 4)) bfly(v[k], v[k | 4], g00, g01, g10, g11);
    }
    {
        GATES(17);
#pragma unroll
        for (int k = 0; k < 16; k++)
            if (!(k & 8)) bfly(v[k], v[k | 8], g00, g01, g10, g11);
    }

    // scatter through GF(2)-linear CNOT map. Per-thread fixed part:
    unsigned f = 0;
#pragma unroll
    for (int kk = 0; kk < 12; kk++) f ^= ((low >> kk) & 1u) ? mk.m[kk] : 0u;
    if (j & 1) f ^= mk.m[14];
    if (j & 2) f ^= mk.m[15];

    float sc = 1.f;
    if (LAST) {
        float nrm = 0.f;
#pragma unroll
        for (int i = 0; i < 64; i++) nrm += partials[batch * 64 + i];
        sc = rsqrtf(nrm);
    }

    // element idx bits: r0->m12, r1->m13, q0->m16, q1->m17 ; gray-code walk
    const unsigned gm0 = mk.m[12], gm1 = mk.m[13], gm2 = mk.m[16], gm3 = mk.m[17];
    unsigned fs = f;
#pragma unroll
    for (int i = 0; i < 16; i++) {
        if (i) {
            const int c = ctzc(i);
            fs ^= (c == 0) ? gm0 : (c == 1) ? gm1 : (c == 2) ? gm2 : gm3;
        }
        const int s = i ^ (i >> 1);
        if (LAST) {
            ((float*)dst)[bb + fs] = sc * sqrtf(fmaf(v[s].x, v[s].x, v[s].y*v[s].y));
        } else {
            ((unsigned*)dst)[bb + fs] = pack(v[s]);
        }
    }
}

// ---- host: CNOT chain as an 18x18 GF(2) matrix -> column masks ----------------
static void chain_masks(int l, Masks* mk) {
    unsigned rows[18];
    for (int j = 0; j < 18; j++) rows[j] = 1u << j;      // new bit j as fn of old bits
    for (int i = 0; i < 18; i++) {
        int cw = (i + l) % 18, tw = (i + l + 1) % 18;    // wires
        rows[17 - tw] ^= rows[17 - cw];                  // bit_t ^= bit_c
    }
    for (int k = 0; k < 18; k++) {                       // transpose into column masks
        unsigned cm = 0;
        for (int j = 0; j < 18; j++) cm |= ((rows[j] >> k) & 1u) << j;
        mk->m[k] = cm;
    }
}

extern "C" void kernel_launch(void* const* d_in, const int* in_sizes, int n_in,
                              void* d_out, int out_size, void* d_ws, size_t ws_size,
                              hipStream_t stream) {
    const float* x      = (const float*)d_in[0];
    const float* params = (const float*)d_in[1];

    char* ws = (char*)d_ws;
    unsigned* bufA  = (unsigned*)ws;                     // 32 MB
    unsigned* bufB  = (unsigned*)(ws + TOTAL * 4);       // 32 MB
    float4*   Utab  = (float4*)(ws + TOTAL * 8);         // 72 * 16 B
    float* partials = (float*)(ws + TOTAL * 8 + 4096);   // 2048 f32

    Masks mk1, mk2;
    chain_masks(0, &mk1);
    chain_masks(1, &mk2);

    passA<1><<<2048, 256, 0, stream>>>((const void*)x, bufA, Utab, partials, params, 0);
    passB<0><<<2048, 256, 0, stream>>>(bufA, (void*)bufB, Utab, partials, 0, mk1);
    passA<0><<<2048, 256, 0, stream>>>((const void*)bufB, bufB, Utab, partials, params, 1);
    passB<1><<<2048, 256, 0, stream>>>(bufB, d_out, Utab, partials, 1, mk2);
}

// Round 6
// 157.947 us; speedup vs baseline: 1.0655x; 1.0655x over previous
//
#include <hip/hip_runtime.h>
#include <hip/hip_fp16.h>

#define NW 18
#define NSTATE (1u << NW)                      // 262144 per batch
#define NBATCH 32
#define TOTAL (NBATCH * (size_t)NSTATE)        // 8388608 elements

typedef float v2f __attribute__((ext_vector_type(2)));
typedef _Float16 h2v __attribute__((ext_vector_type(2)));

struct Masks { unsigned m[18]; };

// ---- packed complex arithmetic via VOP3P op_sel/neg folding -------------------
__device__ __forceinline__ v2f pk_mulsw(v2f g, v2f b) {   // (-g.im*b.im, g.im*b.re)
    v2f d;
    asm("v_pk_mul_f32 %0, %1, %2 op_sel:[1,1] op_sel_hi:[1,0] neg_lo:[1,0]"
        : "=v"(d) : "v"(g), "v"(b));
    return d;
}
__device__ __forceinline__ v2f pk_fmare(v2f g, v2f a, v2f c) { // (g.re*a.re+c.x, g.re*a.im+c.y)
    v2f d;
    asm("v_pk_fma_f32 %0, %1, %2, %3 op_sel:[0,0,0] op_sel_hi:[0,1,1]"
        : "=v"(d) : "v"(g), "v"(a), "v"(c));
    return d;
}
__device__ __forceinline__ v2f pk_fmasw(v2f g, v2f a, v2f c) { // (-g.im*a.im+c.x, g.im*a.re+c.y)
    v2f d;
    asm("v_pk_fma_f32 %0, %1, %2, %3 op_sel:[1,1,0] op_sel_hi:[1,0,1] neg_lo:[1,0,0]"
        : "=v"(d) : "v"(g), "v"(a), "v"(c));
    return d;
}
__device__ __forceinline__ v2f cmul(v2f g, v2f x) { return pk_fmare(g, x, pk_mulsw(g, x)); }
__device__ __forceinline__ v2f cmad(v2f g, v2f x, v2f c) { return pk_fmare(g, x, pk_fmasw(g, x, c)); }

__device__ __forceinline__ void bfly(v2f& a, v2f& b, v2f g00, v2f g01, v2f g10, v2f g11) {
    v2f na = cmad(g00, a, cmul(g01, b));
    v2f nb = cmad(g10, a, cmul(g11, b));
    a = na; b = nb;
}

__device__ __forceinline__ unsigned pack(v2f v) {
    return __builtin_bit_cast(unsigned, __builtin_amdgcn_cvt_pkrtz(v.x, v.y));
}
__device__ __forceinline__ v2f unpack(unsigned u) {
    h2v h = __builtin_bit_cast(h2v, u);
    return (v2f){(float)h.x, (float)h.y};
}

__device__ __forceinline__ int swz(int n) { return n ^ ((n >> 5) & 31); }

__device__ __forceinline__ constexpr int ctzc(int x) {
    int c = 0; while (!(x & 1)) { x >>= 1; c++; } return c;
}

#define GATES(gb)                                                      \
    const float4 G0_ = Ut[(17-(gb))*2+0], G1_ = Ut[(17-(gb))*2+1];     \
    const v2f g00 = {G0_.x, G0_.y}, g01 = {G0_.z, G0_.w};              \
    const v2f g10 = {G1_.x, G1_.y}, g11 = {G1_.z, G1_.w};

// ---- Rot gate matrix from (phi, theta, omega) ---------------------------------
__device__ __forceinline__ void make_gate(const float* __restrict__ p,
                                          float4& G0, float4& G1) {
    float phi = p[0], th = p[1], om = p[2];
    float ch = cosf(th*0.5f), sh = sinf(th*0.5f);
    float a0 = -0.5f*(phi+om), a1 = 0.5f*(phi-om);
    float c0 = cosf(a0), s0 = sinf(a0);
    float c1 = cosf(a1), s1 = sinf(a1);
    G0 = make_float4(c0*ch,  s0*ch, -c1*sh, -s1*sh);
    G1 = make_float4(c1*sh, -s1*sh,  c0*ch, -s0*ch);
}

// ---- pass A: butterflies on bits 0..11 within contiguous 4096 blocks ----------
// 256 threads x 16 elems; 3 register phases of 4 bits, 2 LDS exchanges.
// FIRST=1: src is f32 x; also computes all 36 gates (block 0 -> global Utab),
// accumulates per-block sum-of-squares into partials. State stays UNSCALED.
template<int FIRST>
__global__ __launch_bounds__(256, 6) void passA(const void* __restrict__ src,
                                                unsigned* __restrict__ dst,
                                                float4* __restrict__ Utab,
                                                float* __restrict__ partials,
                                                const float* __restrict__ params,
                                                int layer) {
    __shared__ unsigned sm[4096];   // 16 KB
    __shared__ float4 gl[72];       // 36 gates x 2
    __shared__ float wsum[4];
    const int t = threadIdx.x;      // 0..255
    const size_t base = (size_t)blockIdx.x * 4096;
    v2f v[16];
    const float4* Ut;
    float ss = 0.f;

    if (FIRST) {
        const float4* xs = (const float4*)((const float*)src + base + (size_t)t * 16);

        if (t < 36) {                       // both layers' gates, redundantly per block
            float4 G0, G1;
            make_gate(params + t*3, G0, G1);
            gl[t*2] = G0; gl[t*2+1] = G1;
            if (blockIdx.x == 0) { Utab[t*2] = G0; Utab[t*2+1] = G1; }
        }

#pragma unroll
        for (int j = 0; j < 4; j++) {
            float4 q = xs[j];
            v[j*4+0] = (v2f){q.x, 0.f};
            v[j*4+1] = (v2f){q.y, 0.f};
            v[j*4+2] = (v2f){q.z, 0.f};
            v[j*4+3] = (v2f){q.w, 0.f};
            ss += q.x*q.x + q.y*q.y + q.z*q.z + q.w*q.w;
        }
#pragma unroll
        for (int m = 32; m >= 1; m >>= 1) ss += __shfl_xor(ss, m, 64);
        if ((t & 63) == 0) wsum[t >> 6] = ss;
        __syncthreads();                    // gates (and wsum) visible
        Ut = gl;                            // layer 0 lives at gl[0..35]
    } else {
        const uint4* xs = (const uint4*)((const unsigned*)src + base + (size_t)t * 16);
#pragma unroll
        for (int j = 0; j < 4; j++) {
            uint4 q = xs[j];
            v[j*4+0] = unpack(q.x);
            v[j*4+1] = unpack(q.y);
            v[j*4+2] = unpack(q.z);
            v[j*4+3] = unpack(q.w);
        }
        Ut = (const float4*)Utab + (size_t)layer * 36;
    }

    // phase 1: bits 0..3 (element k = n&15)
#pragma unroll
    for (int b = 0; b < 4; b++) {
        GATES(b);
#pragma unroll
        for (int k = 0; k < 16; k++)
            if (!(k & (1 << b))) bfly(v[k], v[k | (1 << b)], g00, g01, g10, g11);
    }

    // exchange 1: L1 n = (t<<4)|k  ->  L2 n = (t&15) | k<<4 | (t>>4)<<8
#pragma unroll
    for (int k = 0; k < 16; k++)
        sm[swz((t << 4) | k)] = pack(v[k]);
    __syncthreads();
    if (FIRST && t == 0)
        partials[blockIdx.x] = wsum[0] + wsum[1] + wsum[2] + wsum[3];
#pragma unroll
    for (int k = 0; k < 16; k++)
        v[k] = unpack(sm[swz((t & 15) | (k << 4) | ((t >> 4) << 8))]);

    // phase 2: bits 4..7 (element k = (n>>4)&15)
#pragma unroll
    for (int b = 4; b < 8; b++) {
        GATES(b);
        const int pb = 1 << (b - 4);
#pragma unroll
        for (int k = 0; k < 16; k++)
            if (!(k & pb)) bfly(v[k], v[k | pb], g00, g01, g10, g11);
    }

    // exchange 2: write back own L2 slots (disjoint, no pre-sync), read L3
#pragma unroll
    for (int k = 0; k < 16; k++)
        sm[swz((t & 15) | (k << 4) | ((t >> 4) << 8))] = pack(v[k]);
    __syncthreads();
#pragma unroll
    for (int k = 0; k < 16; k++)
        v[k] = unpack(sm[swz(t | (k << 8))]);

    // phase 3: bits 8..11 (element k = (n>>8)&15)
#pragma unroll
    for (int b = 8; b < 12; b++) {
        GATES(b);
        const int pb = 1 << (b - 8);
#pragma unroll
        for (int k = 0; k < 16; k++)
            if (!(k & pb)) bfly(v[k], v[k | pb], g00, g01, g10, g11);
    }

    // store (L3 layout: lane-contiguous, coalesced)
#pragma unroll
    for (int k = 0; k < 16; k++)
        dst[base + (t | (k << 8))] = pack(v[k]);
}

// ---- pass B: butterflies on bits 12..17, then CNOT-chain scatter --------------
// 256 threads x 16 elems. Block = 64 contiguous lows x all 64 highs (bits 12..17).
// LAST=1: write sc*|amp| as f32 to out; else packed fp16x2 state.
template<int LAST>
__global__ __launch_bounds__(256, 6) void passB(const unsigned* __restrict__ src,
                                                void* __restrict__ dst,
                                                const float4* __restrict__ Utab,
                                                const float* __restrict__ partials,
                                                int layer, Masks mk) {
    __shared__ unsigned sm[4096];   // 16 KB
    const int t = threadIdx.x;                 // 0..255
    const unsigned blk = blockIdx.x;           // 2048 blocks
    const unsigned batch = blk >> 6;
    const unsigned chunk = blk & 63;
    const unsigned low = chunk * 64 + (t & 63);   // 12-bit low index
    const unsigned j = t >> 6;                 // 0..3 (wave id)
    const size_t bb = (size_t)batch << NW;

    v2f v[16];
    // phase-1 ownership: h = (j<<4)|k  (k = h bits 0..3 = state bits 12..15)
#pragma unroll
    for (int k = 0; k < 16; k++) {
        unsigned h = (j << 4) | k;
        v[k] = unpack(src[bb + ((size_t)h << 12) + low]);
    }

    const float4* Ut = Utab + (size_t)layer * 36;
#pragma unroll
    for (int b = 12; b < 16; b++) {
        GATES(b);
        const int pb = 1 << (b - 12);
#pragma unroll
        for (int k = 0; k < 16; k++)
            if (!(k & pb)) bfly(v[k], v[k | pb], g00, g01, g10, g11);
    }

    // exchange: slot n = (h<<6) | (t&63); lanes consecutive -> conflict-free
#pragma unroll
    for (int k = 0; k < 16; k++) {
        unsigned h = (j << 4) | k;
        sm[(h << 6) | (t & 63)] = pack(v[k]);
    }
    __syncthreads();
    // phase-2 ownership: h = (q<<4) | (j<<2) | r, element idx = (q<<2)|r
#pragma unroll
    for (int q = 0; q < 4; q++)
#pragma unroll
        for (int r = 0; r < 4; r++) {
            unsigned h = (q << 4) | (j << 2) | r;
            v[(q << 2) | r] = unpack(sm[(h << 6) | (t & 63)]);
        }

    // bit 16 (wire 1): pairs idx, idx^4 ; bit 17 (wire 0): pairs idx, idx^8
    {
        GATES(16);
#pragma unroll
        for (int k = 0; k < 16; k++)
            if (!(k & 4)) bfly(v[k], v[k | 4], g00, g01, g10, g11);
    }
    {
        GATES(17);
#pragma unroll
        for (int k = 0; k < 16; k++)
            if (!(k & 8)) bfly(v[k], v[k | 8], g00, g01, g10, g11);
    }

    // scatter through GF(2)-linear CNOT map. Per-thread fixed part:
    unsigned f = 0;
#pragma unroll
    for (int kk = 0; kk < 12; kk++) f ^= ((low >> kk) & 1u) ? mk.m[kk] : 0u;
    if (j & 1) f ^= mk.m[14];
    if (j & 2) f ^= mk.m[15];

    float sc = 1.f;
    if (LAST) {
        float nrm = 0.f;
#pragma unroll
        for (int i = 0; i < 64; i++) nrm += partials[batch * 64 + i];
        sc = rsqrtf(nrm);
    }

    // element idx bits: r0->m12, r1->m13, q0->m16, q1->m17 ; gray-code walk
    const unsigned gm0 = mk.m[12], gm1 = mk.m[13], gm2 = mk.m[16], gm3 = mk.m[17];
    unsigned fs = f;
#pragma unroll
    for (int i = 0; i < 16; i++) {
        if (i) {
            const int c = ctzc(i);
            fs ^= (c == 0) ? gm0 : (c == 1) ? gm1 : (c == 2) ? gm2 : gm3;
        }
        const int s = i ^ (i >> 1);
        if (LAST) {
            ((float*)dst)[bb + fs] = sc * sqrtf(fmaf(v[s].x, v[s].x, v[s].y*v[s].y));
        } else {
            ((unsigned*)dst)[bb + fs] = pack(v[s]);
        }
    }
}

// ---- host: CNOT chain as an 18x18 GF(2) matrix -> column masks ----------------
static void chain_masks(int l, Masks* mk) {
    unsigned rows[18];
    for (int j = 0; j < 18; j++) rows[j] = 1u << j;      // new bit j as fn of old bits
    for (int i = 0; i < 18; i++) {
        int cw = (i + l) % 18, tw = (i + l + 1) % 18;    // wires
        rows[17 - tw] ^= rows[17 - cw];                  // bit_t ^= bit_c
    }
    for (int k = 0; k < 18; k++) {                       // transpose into column masks
        unsigned cm = 0;
        for (int j = 0; j < 18; j++) cm |= ((rows[j] >> k) & 1u) << j;
        mk->m[k] = cm;
    }
}

extern "C" void kernel_launch(void* const* d_in, const int* in_sizes, int n_in,
                              void* d_out, int out_size, void* d_ws, size_t ws_size,
                              hipStream_t stream) {
    const float* x      = (const float*)d_in[0];
    const float* params = (const float*)d_in[1];

    char* ws = (char*)d_ws;
    unsigned* bufA  = (unsigned*)ws;                     // 32 MB
    unsigned* bufB  = (unsigned*)(ws + TOTAL * 4);       // 32 MB
    float4*   Utab  = (float4*)(ws + TOTAL * 8);         // 72 * 16 B
    float* partials = (float*)(ws + TOTAL * 8 + 4096);   // 2048 f32

    Masks mk1, mk2;
    chain_masks(0, &mk1);
    chain_masks(1, &mk2);

    passA<1><<<2048, 256, 0, stream>>>((const void*)x, bufA, Utab, partials, params, 0);
    passB<0><<<2048, 256, 0, stream>>>(bufA, (void*)bufB, Utab, partials, 0, mk1);
    passA<0><<<2048, 256, 0, stream>>>((const void*)bufB, bufB, Utab, partials, params, 1);
    passB<1><<<2048, 256, 0, stream>>>(bufB, d_out, Utab, partials, 1, mk2);
}

// Round 7
// 147.101 us; speedup vs baseline: 1.1440x; 1.0737x over previous
//
#include <hip/hip_runtime.h>
#include <hip/hip_fp16.h>

#define NW 18
#define NSTATE (1u << NW)                      // 262144 per batch
#define NBATCH 32
#define TOTAL (NBATCH * (size_t)NSTATE)        // 8388608 elements

typedef float v2f __attribute__((ext_vector_type(2)));
typedef _Float16 h2v __attribute__((ext_vector_type(2)));

struct Masks { unsigned m[18]; };
struct G4 { v2f a, b, c, d; };   // g00, g01, g10, g11

// ---- packed complex arithmetic via VOP3P op_sel/neg folding -------------------
__device__ __forceinline__ v2f pk_mulsw(v2f g, v2f b) {   // (-g.im*b.im, g.im*b.re)
    v2f d;
    asm("v_pk_mul_f32 %0, %1, %2 op_sel:[1,1] op_sel_hi:[1,0] neg_lo:[1,0]"
        : "=v"(d) : "v"(g), "v"(b));
    return d;
}
__device__ __forceinline__ v2f pk_fmare(v2f g, v2f a, v2f c) { // (g.re*a.re+c.x, g.re*a.im+c.y)
    v2f d;
    asm("v_pk_fma_f32 %0, %1, %2, %3 op_sel:[0,0,0] op_sel_hi:[0,1,1]"
        : "=v"(d) : "v"(g), "v"(a), "v"(c));
    return d;
}
__device__ __forceinline__ v2f pk_fmasw(v2f g, v2f a, v2f c) { // (-g.im*a.im+c.x, g.im*a.re+c.y)
    v2f d;
    asm("v_pk_fma_f32 %0, %1, %2, %3 op_sel:[1,1,0] op_sel_hi:[1,0,1] neg_lo:[1,0,0]"
        : "=v"(d) : "v"(g), "v"(a), "v"(c));
    return d;
}
__device__ __forceinline__ v2f cmul(v2f g, v2f x) { return pk_fmare(g, x, pk_mulsw(g, x)); }
__device__ __forceinline__ v2f cmad(v2f g, v2f x, v2f c) { return pk_fmare(g, x, pk_fmasw(g, x, c)); }

// butterfly: (x,y) <- (g00*x + g01*y, g10*x + g11*y); x MUST be the parity-0 elem
__device__ __forceinline__ void bflyG(v2f& x, v2f& y, const G4 g) {
    v2f nx = cmad(g.a, x, cmul(g.b, y));
    v2f ny = cmad(g.c, x, cmul(g.d, y));
    x = nx; y = ny;
}

__device__ __forceinline__ G4 loadg(const float4* __restrict__ Ut, int gb) {
    float4 G0 = Ut[(17 - gb) * 2], G1 = Ut[(17 - gb) * 2 + 1];
    G4 g; g.a = (v2f){G0.x, G0.y}; g.b = (v2f){G0.z, G0.w};
    g.c = (v2f){G1.x, G1.y}; g.d = (v2f){G1.z, G1.w};
    return g;
}
// p==1 -> row/col-swapped matrix (use when first arg is the parity-1 elem)
__device__ __forceinline__ G4 selg(const G4 g, unsigned p) {
    G4 r; r.a = p ? g.d : g.a; r.b = p ? g.c : g.b;
    r.c = p ? g.b : g.c; r.d = p ? g.a : g.d;
    return r;
}

// fp16x2 pack/unpack
__device__ __forceinline__ unsigned pack(v2f v) {
    return __builtin_bit_cast(unsigned, __builtin_amdgcn_cvt_pkrtz(v.x, v.y));
}
__device__ __forceinline__ v2f unpack(unsigned u) {
    h2v h = __builtin_bit_cast(h2v, u);
    return (v2f){(float)h.x, (float)h.y};
}

__device__ __forceinline__ int swz(int n) { return n ^ ((n >> 5) & 31); }
#define SWZ2(L) ((unsigned)(L) ^ (((((unsigned)(L)) >> 5) ^ (((unsigned)(L)) >> 6)) & 1u))

__device__ __forceinline__ constexpr int ctzc(int x) {
    int c = 0; while (!(x & 1)) { x >>= 1; c++; } return c;
}
__device__ __forceinline__ unsigned pfx18(unsigned x) {  // u_k = x_0^...^x_k
    x ^= x << 1; x ^= x << 2; x ^= x << 4; x ^= x << 8; x ^= x << 16;
    return x & 0x3FFFFu;
}

// ---- Rot gate matrix from (phi, theta, omega) ---------------------------------
__device__ __forceinline__ void make_gate(const float* __restrict__ p,
                                          float4& G0, float4& G1) {
    float phi = p[0], th = p[1], om = p[2];
    float ch = cosf(th * 0.5f), sh = sinf(th * 0.5f);
    float a0 = -0.5f * (phi + om), a1 = 0.5f * (phi - om);
    float c0 = cosf(a0), s0 = sinf(a0);
    float c1 = cosf(a1), s1 = sinf(a1);
    G0 = make_float4(c0 * ch, s0 * ch, -c1 * sh, -s1 * sh);
    G1 = make_float4(c1 * sh, -s1 * sh, c0 * ch, -s0 * ch);
}

// ---- pass 1: layer-0 gates on bits 0..11; fused norm + gate prep --------------
// Utab layout: [0..35] layer0, [36..71] layer1, [72..107] layer1 SWAPPED.
__global__ __launch_bounds__(256, 4) void pass1(const float* __restrict__ src,
                                                unsigned* __restrict__ dst,
                                                float4* __restrict__ Utab,
                                                float* __restrict__ partials,
                                                const float* __restrict__ params) {
    __shared__ unsigned sm[4096];   // 16 KB
    __shared__ float4 gl[36];       // layer-0 gates
    __shared__ float wsum[4];
    const int t = threadIdx.x;
    const size_t base = (size_t)blockIdx.x * 4096;
    v2f v[16];
    float ss = 0.f;

    const float4* xs = (const float4*)(src + base + (size_t)t * 16);

    if (t < 36) {
        float4 G0, G1; make_gate(params + t * 3, G0, G1);
        if (t < 18) { gl[t * 2] = G0; gl[t * 2 + 1] = G1; }
        if (blockIdx.x == 0) {
            Utab[t * 2] = G0; Utab[t * 2 + 1] = G1;
            if (t >= 18) {   // swapped layer-1 copy
                Utab[72 + (t - 18) * 2 + 0] = make_float4(G1.z, G1.w, G1.x, G1.y);
                Utab[72 + (t - 18) * 2 + 1] = make_float4(G0.z, G0.w, G0.x, G0.y);
            }
        }
    }

#pragma unroll
    for (int j = 0; j < 4; j++) {
        float4 q = xs[j];
        v[j * 4 + 0] = (v2f){q.x, 0.f};
        v[j * 4 + 1] = (v2f){q.y, 0.f};
        v[j * 4 + 2] = (v2f){q.z, 0.f};
        v[j * 4 + 3] = (v2f){q.w, 0.f};
        ss += q.x * q.x + q.y * q.y + q.z * q.z + q.w * q.w;
    }
#pragma unroll
    for (int m = 32; m >= 1; m >>= 1) ss += __shfl_xor(ss, m, 64);
    if ((t & 63) == 0) wsum[t >> 6] = ss;
    __syncthreads();   // gates + wsum visible

    const float4* Ut = gl;

    // phase 1: bits 0..3
#pragma unroll
    for (int b = 0; b < 4; b++) {
        G4 g = loadg(Ut, b);
#pragma unroll
        for (int k = 0; k < 16; k++)
            if (!(k & (1 << b))) bflyG(v[k], v[k | (1 << b)], g);
    }
    // exchange 1
#pragma unroll
    for (int k = 0; k < 16; k++)
        sm[swz((t << 4) | k)] = pack(v[k]);
    __syncthreads();
    if (t == 0) partials[blockIdx.x] = wsum[0] + wsum[1] + wsum[2] + wsum[3];
#pragma unroll
    for (int k = 0; k < 16; k++)
        v[k] = unpack(sm[swz((t & 15) | (k << 4) | ((t >> 4) << 8))]);
    // phase 2: bits 4..7
#pragma unroll
    for (int b = 4; b < 8; b++) {
        G4 g = loadg(Ut, b);
        const int pb = 1 << (b - 4);
#pragma unroll
        for (int k = 0; k < 16; k++)
            if (!(k & pb)) bflyG(v[k], v[k | pb], g);
    }
    // exchange 2
#pragma unroll
    for (int k = 0; k < 16; k++)
        sm[swz((t & 15) | (k << 4) | ((t >> 4) << 8))] = pack(v[k]);
    __syncthreads();
#pragma unroll
    for (int k = 0; k < 16; k++)
        v[k] = unpack(sm[swz(t | (k << 8))]);
    // phase 3: bits 8..11
#pragma unroll
    for (int b = 8; b < 12; b++) {
        G4 g = loadg(Ut, b);
        const int pb = 1 << (b - 8);
#pragma unroll
        for (int k = 0; k < 16; k++)
            if (!(k & pb)) bflyG(v[k], v[k | pb], g);
    }
    // store, x-order
#pragma unroll
    for (int k = 0; k < 16; k++)
        dst[base + (t | (k << 8))] = pack(v[k]);
}

// ---- pass 2: layer-0 bits 12..17 + virtual layer-1 gates {16,17,0,13,14,15} ---
// Tile: lows x0..5 (lane) x highs x12..17; mid x6..11 = chunk. Writes u-order.
__global__ __launch_bounds__(256, 4) void pass2(const unsigned* __restrict__ src,
                                                unsigned* __restrict__ dst,
                                                const float4* __restrict__ Utab) {
    __shared__ unsigned sm[4096];
    const int t = threadIdx.x;
    const unsigned blk = blockIdx.x;
    const unsigned batch = blk >> 6, chunk = blk & 63;
    const size_t bb = (size_t)batch << NW;
    const int lane6 = t & 63, j2 = t >> 6;
    const float4* Ut0  = Utab;
    const float4* Ut1  = Utab + 36;
    const float4* Ut1s = Utab + 72;
    v2f v[16];

    // load: element k = x12..15, j2 = x16..17
#pragma unroll
    for (int k = 0; k < 16; k++)
        v[k] = unpack(src[bb + ((size_t)((j2 << 4) | k) << 12) + (chunk << 6) + lane6]);

    // phase 1: layer-0 bits 12..15 on k-bits 0..3
#pragma unroll
    for (int b = 0; b < 4; b++) {
        G4 g = loadg(Ut0, 12 + b);
#pragma unroll
        for (int k = 0; k < 16; k++)
            if (!(k & (1 << b))) bflyG(v[k], v[k | (1 << b)], g);
    }

    // exchange 1: slot L = (x17 x16 x15 x14 x13 x12)<<6 | (x5..x1 x0)
#pragma unroll
    for (int k = 0; k < 16; k++)
        sm[SWZ2((((j2 << 4) | k) << 6) | lane6)] = pack(v[k]);
    __syncthreads();
    // phase-2 ownership: elem bits (k0,k1,k2,k3) = (x0,x15,x16,x17); fixed l5=x1..5, m3=x12..14
    const int l5 = t & 31, m3 = t >> 5;
#pragma unroll
    for (int k = 0; k < 16; k++) {
        int L = ((((k >> 3) << 5) | (((k >> 2) & 1) << 4) | (((k >> 1) & 1) << 3) | m3) << 6)
                | (l5 << 1) | (k & 1);
        v[k] = unpack(sm[SWZ2(L)]);
    }

    // layer-0 bit 16 (elem bit 2), bit 17 (elem bit 3)
    { G4 g = loadg(Ut0, 16);
#pragma unroll
      for (int k = 0; k < 16; k++) if (!(k & 4)) bflyG(v[k], v[k | 4], g); }
    { G4 g = loadg(Ut0, 17);
#pragma unroll
      for (int k = 0; k < 16; k++) if (!(k & 8)) bflyG(v[k], v[k | 8], g); }

    // V16: c={15,16}->^6 ; sel parity = x16^x17 = k2^k3 (compile-time)
    { G4 g = loadg(Ut1, 16);
#pragma unroll
      for (int k = 0; k < 16; k++) if (!(k & 2)) {
          const int q = k ^ 6, pe = ((k >> 2) ^ (k >> 3)) & 1;
          if (pe) bflyG(v[q], v[k], g); else bflyG(v[k], v[q], g);
      } }

    // per-thread parity of x1..x14 for V17 / V0
    const unsigned ptv = (unsigned)((__popc(l5) + __popc((int)chunk) + __popc(m3)) & 1);

    // V17: c={16,17}->^12 ; sel = x0^x15^x16 ^ pt = (k0^k1^k2) ^ ptv
    { G4 gn = loadg(Ut1, 17);
      G4 cA = selg(gn, ptv), cB = selg(gn, ptv ^ 1u);
#pragma unroll
      for (int k = 0; k < 16; k++) if (!(k & 4)) {
          const int q = k ^ 12, pe = (k ^ (k >> 1) ^ (k >> 2)) & 1;
          bflyG(v[k], v[q], pe ? cB : cA);
      } }

    // V0: c={0,16,17}->^13 ; sel = (k0^k1^k2^k3) ^ ptv
    { G4 gn = loadg(Ut1, 0);
      G4 cA = selg(gn, ptv), cB = selg(gn, ptv ^ 1u);
#pragma unroll
      for (int k = 0; k < 16; k++) if (!(k & 1)) {
          const int q = k ^ 13, pe = (k ^ (k >> 1) ^ (k >> 2) ^ (k >> 3)) & 1;
          bflyG(v[k], v[q], pe ? cB : cA);
      } }

    // exchange 2: write back own slots, re-tile to phase-1 ownership
#pragma unroll
    for (int k = 0; k < 16; k++) {
        int L = ((((k >> 3) << 5) | (((k >> 2) & 1) << 4) | (((k >> 1) & 1) << 3) | m3) << 6)
                | (l5 << 1) | (k & 1);
        sm[SWZ2(L)] = pack(v[k]);
    }
    __syncthreads();
#pragma unroll
    for (int k = 0; k < 16; k++)
        v[k] = unpack(sm[SWZ2((((j2 << 4) | k) << 6) | lane6)]);

    // phase 3: V13,V14,V15 on elem bits k=x12..15 ; pt3 = parity(x16,x17) wave-uniform
    const unsigned pt3 = (unsigned)((j2 ^ (j2 >> 1)) & 1);
    const float4* U3 = pt3 ? Ut1s : Ut1;
    { G4 g = loadg(U3, 13);   // c={12,13}->^3 ; pe = k1^k2^k3
#pragma unroll
      for (int k = 0; k < 16; k++) if (!(k & 1)) {
          const int q = k ^ 3, pe = ((k >> 1) ^ (k >> 2) ^ (k >> 3)) & 1;
          if (pe) bflyG(v[q], v[k], g); else bflyG(v[k], v[q], g);
      } }
    { G4 g = loadg(U3, 14);   // c={13,14}->^6 ; pe = k2^k3
#pragma unroll
      for (int k = 0; k < 16; k++) if (!(k & 2)) {
          const int q = k ^ 6, pe = ((k >> 2) ^ (k >> 3)) & 1;
          if (pe) bflyG(v[q], v[k], g); else bflyG(v[k], v[q], g);
      } }
    { G4 g = loadg(U3, 15);   // c={14,15}->^12 ; pe = k3
#pragma unroll
      for (int k = 0; k < 16; k++) if (!(k & 4)) {
          const int q = k ^ 12, pe = (k >> 3) & 1;
          if (pe) bflyG(v[q], v[k], g); else bflyG(v[k], v[q], g);
      } }

    // write in u-order: u = prefix-xor(x); gray-walk elem bits x12..15
    const unsigned fixedx = ((unsigned)j2 << 16) | (chunk << 6) | (unsigned)lane6;
    unsigned us = pfx18(fixedx);
#pragma unroll
    for (int i = 0; i < 16; i++) {
        if (i) {
            const int c = ctzc(i);
            us ^= (c == 0) ? 0x3F000u : (c == 1) ? 0x3E000u : (c == 2) ? 0x3C000u : 0x38000u;
        }
        const int s = i ^ (i >> 1);
        dst[bb + us] = pack(v[s]);
    }
}

// ---- pass 3: virtual gates j=1..12 = plain butterflies on u-bits 0..11 --------
// u17 (tile-uniform) selects the pre-swapped gate table. Ends with combined
// scatter out[W(u)] = sc*|amp| (W = P2*P1*T^-1 column masks).
__global__ __launch_bounds__(256, 4) void pass3(const unsigned* __restrict__ src,
                                                float* __restrict__ out,
                                                const float4* __restrict__ Utab,
                                                const float* __restrict__ partials,
                                                Masks W) {
    __shared__ unsigned sm[4096];
    const int t = threadIdx.x;
    const unsigned blk = blockIdx.x;
    const unsigned batch = blk >> 6, loc = blk & 63;
    const size_t bb = (size_t)batch << NW;
    const size_t base = bb + ((size_t)loc << 12);
    const unsigned u17 = (loc >> 5) & 1;
    const float4* Ut = Utab + (u17 ? 72 : 36);
    v2f v[16];

    const uint4* xs = (const uint4*)(src + base + (size_t)t * 16);
#pragma unroll
    for (int j = 0; j < 4; j++) {
        uint4 q = xs[j];
        v[j * 4 + 0] = unpack(q.x);
        v[j * 4 + 1] = unpack(q.y);
        v[j * 4 + 2] = unpack(q.z);
        v[j * 4 + 3] = unpack(q.w);
    }

    // phase 1: u-bits 0..3 -> gates j=1..4
#pragma unroll
    for (int b = 0; b < 4; b++) {
        G4 g = loadg(Ut, b + 1);
#pragma unroll
        for (int k = 0; k < 16; k++)
            if (!(k & (1 << b))) bflyG(v[k], v[k | (1 << b)], g);
    }
#pragma unroll
    for (int k = 0; k < 16; k++)
        sm[swz((t << 4) | k)] = pack(v[k]);
    __syncthreads();
#pragma unroll
    for (int k = 0; k < 16; k++)
        v[k] = unpack(sm[swz((t & 15) | (k << 4) | ((t >> 4) << 8))]);
    // phase 2: u-bits 4..7 -> gates j=5..8
#pragma unroll
    for (int b = 4; b < 8; b++) {
        G4 g = loadg(Ut, b + 1);
        const int pb = 1 << (b - 4);
#pragma unroll
        for (int k = 0; k < 16; k++)
            if (!(k & pb)) bflyG(v[k], v[k | pb], g);
    }
#pragma unroll
    for (int k = 0; k < 16; k++)
        sm[swz((t & 15) | (k << 4) | ((t >> 4) << 8))] = pack(v[k]);
    __syncthreads();
#pragma unroll
    for (int k = 0; k < 16; k++)
        v[k] = unpack(sm[swz(t | (k << 8))]);
    // phase 3: u-bits 8..11 -> gates j=9..12
#pragma unroll
    for (int b = 8; b < 12; b++) {
        G4 g = loadg(Ut, b + 1);
        const int pb = 1 << (b - 8);
#pragma unroll
        for (int k = 0; k < 16; k++)
            if (!(k & pb)) bflyG(v[k], v[k | pb], g);
    }

    // batch norm
    float nrm = 0.f;
#pragma unroll
    for (int i = 0; i < 64; i++) nrm += partials[batch * 64 + i];
    const float sc = rsqrtf(nrm);

    // scatter: u = loc<<12 | k<<8 | t ; out addr = XOR of W cols over set u-bits
    unsigned f = 0;
    const unsigned fx = (loc << 12) | (unsigned)t;
#pragma unroll
    for (int i = 0; i < 18; i++) {
        if (i >= 8 && i < 12) continue;
        if ((fx >> i) & 1) f ^= W.m[i];
    }
    unsigned fs = f;
#pragma unroll
    for (int i = 0; i < 16; i++) {
        if (i) fs ^= W.m[8 + ctzc(i)];
        const int s = i ^ (i >> 1);
        out[bb + fs] = sc * sqrtf(fmaf(v[s].x, v[s].x, v[s].y * v[s].y));
    }
}

// ---- host: GF(2) machinery ----------------------------------------------------
static unsigned apply_m(const unsigned* col, unsigned x) {
    unsigned r = 0;
    for (int i = 0; i < 18; i++) if ((x >> i) & 1) r ^= col[i];
    return r;
}
// columns of the CNOT-chain index permutation P_l : col[i] = P(e_i)
static void perm_cols(int l, unsigned* col) {
    for (int i = 0; i < 18; i++) {
        unsigned x = 1u << i;
        for (int g = 0; g < 18; g++) {
            int cb = 17 - ((g + l) % 18), tb = 17 - ((g + l + 1) % 18);
            if ((x >> cb) & 1) x ^= 1u << tb;
        }
        col[i] = x;
    }
}

extern "C" void kernel_launch(void* const* d_in, const int* in_sizes, int n_in,
                              void* d_out, int out_size, void* d_ws, size_t ws_size,
                              hipStream_t stream) {
    const float* x      = (const float*)d_in[0];
    const float* params = (const float*)d_in[1];

    char* ws = (char*)d_ws;
    unsigned* bufA  = (unsigned*)ws;                     // 32 MB
    unsigned* bufB  = (unsigned*)(ws + TOTAL * 4);       // 32 MB
    float4*   Utab  = (float4*)(ws + TOTAL * 8);         // 108 * 16 B
    float* partials = (float*)(ws + TOTAL * 8 + 4096);   // 2048 f32

    unsigned P1c[18], P2c[18];
    perm_cols(0, P1c);
    perm_cols(1, P2c);
    Masks W;   // W = P2 * P1 * T^-1 ; Tinv col[k] = {k, k+1}
    for (int k = 0; k < 18; k++) {
        unsigned tinv = (1u << k) | (k < 17 ? (1u << (k + 1)) : 0u);
        W.m[k] = apply_m(P2c, apply_m(P1c, tinv));
    }

    pass1<<<2048, 256, 0, stream>>>(x, bufA, Utab, partials, params);
    pass2<<<2048, 256, 0, stream>>>(bufA, bufB, Utab);
    pass3<<<2048, 256, 0, stream>>>(bufB, (float*)d_out, Utab, partials, W);
}

// Round 8
// 141.551 us; speedup vs baseline: 1.1889x; 1.0392x over previous
//
#include <hip/hip_runtime.h>
#include <hip/hip_fp16.h>

#define NW 18
#define NSTATE (1u << NW)                      // 262144 per batch
#define NBATCH 32
#define TOTAL (NBATCH * (size_t)NSTATE)        // 8388608 elements

typedef _Float16 h2 __attribute__((ext_vector_type(2)));

struct Masks { unsigned m[18]; };
struct G4h { h2 a, b, c, d; };   // g00, g01, g10, g11 (packed f16 complex)

// ---- packed f16 complex arithmetic via VOP3P op_sel/neg folding ---------------
__device__ __forceinline__ h2 pk_mulsw(h2 g, h2 b) {   // (-g.im*b.im, g.im*b.re)
    h2 d;
    asm("v_pk_mul_f16 %0, %1, %2 op_sel:[1,1] op_sel_hi:[1,0] neg_lo:[1,0]"
        : "=v"(d) : "v"(g), "v"(b));
    return d;
}
__device__ __forceinline__ h2 pk_fmare(h2 g, h2 a, h2 c) { // (g.re*a.re+c.lo, g.re*a.im+c.hi)
    h2 d;
    asm("v_pk_fma_f16 %0, %1, %2, %3 op_sel:[0,0,0] op_sel_hi:[0,1,1]"
        : "=v"(d) : "v"(g), "v"(a), "v"(c));
    return d;
}
__device__ __forceinline__ h2 pk_fmasw(h2 g, h2 a, h2 c) { // (-g.im*a.im+c.lo, g.im*a.re+c.hi)
    h2 d;
    asm("v_pk_fma_f16 %0, %1, %2, %3 op_sel:[1,1,0] op_sel_hi:[1,0,1] neg_lo:[1,0,0]"
        : "=v"(d) : "v"(g), "v"(a), "v"(c));
    return d;
}
__device__ __forceinline__ h2 cmul(h2 g, h2 x) { return pk_fmare(g, x, pk_mulsw(g, x)); }
__device__ __forceinline__ h2 cmad(h2 g, h2 x, h2 c) { return pk_fmare(g, x, pk_fmasw(g, x, c)); }

// butterfly: (x,y) <- (g00*x + g01*y, g10*x + g11*y); x MUST be the parity-0 elem
__device__ __forceinline__ void bflyG(h2& x, h2& y, const G4h g) {
    h2 nx = cmad(g.a, x, cmul(g.b, y));
    h2 ny = cmad(g.c, x, cmul(g.d, y));
    x = nx; y = ny;
}

__device__ __forceinline__ unsigned U(h2 v) { return __builtin_bit_cast(unsigned, v); }
__device__ __forceinline__ h2 H(unsigned u) { return __builtin_bit_cast(h2, u); }

__device__ __forceinline__ G4h loadg(const uint4* __restrict__ p, int bit) {
    uint4 q = p[17 - bit];    // table indexed by wire = 17-bit
    G4h g; g.a = H(q.x); g.b = H(q.y); g.c = H(q.z); g.d = H(q.w);
    return g;
}
// p==1 -> row/col-swapped matrix (use when first arg is the parity-1 elem)
__device__ __forceinline__ G4h selg(const G4h g, unsigned p) {
    G4h r; r.a = p ? g.d : g.a; r.b = p ? g.c : g.b;
    r.c = p ? g.b : g.c; r.d = p ? g.a : g.d;
    return r;
}

// 4-alignment-preserving LDS swizzle (b128-safe); all patterns <=2 lanes/bank
__device__ __forceinline__ int swz4(int n) { return n ^ ((n >> 5) & 28); }
#define SWZ2(L) ((unsigned)(L) ^ (((((unsigned)(L)) >> 5) ^ (((unsigned)(L)) >> 6)) & 1u))

__device__ __forceinline__ constexpr int ctzc(int x) {
    int c = 0; while (!(x & 1)) { x >>= 1; c++; } return c;
}
__device__ __forceinline__ unsigned pfx18(unsigned x) {  // u_k = x_0^...^x_k
    x ^= x << 1; x ^= x << 2; x ^= x << 4; x ^= x << 8; x ^= x << 16;
    return x & 0x3FFFFu;
}

// ---- Rot gate matrix -> packed f16 uint4 (RTN via _Float16 cast) --------------
__device__ __forceinline__ uint4 gate_u4(const float* __restrict__ p) {
    float phi = p[0], th = p[1], om = p[2];
    float ch = cosf(th * 0.5f), sh = sinf(th * 0.5f);
    float a0 = -0.5f * (phi + om), a1 = 0.5f * (phi - om);
    float c0 = cosf(a0), s0 = sinf(a0), c1 = cosf(a1), s1 = sinf(a1);
    auto pk = [](float x, float y) {
        h2 h = {(_Float16)x, (_Float16)y};
        return __builtin_bit_cast(unsigned, h);
    };
    // g00=(c0ch,s0ch) g01=(-c1sh,-s1sh) g10=(c1sh,-s1sh) g11=(c0ch,-s0ch)
    return make_uint4(pk(c0 * ch, s0 * ch), pk(-c1 * sh, -s1 * sh),
                      pk(c1 * sh, -s1 * sh), pk(c0 * ch, -s0 * ch));
}

// ---- pass 1: layer-0 gates on bits 0..11; fused norm + gate prep --------------
// Uh layout: [0..17] L0 by wire, [18..35] L1, [36..53] L1 swapped.
__global__ __launch_bounds__(256, 8) void pass1(const float* __restrict__ src,
                                                unsigned* __restrict__ dst,
                                                uint4* __restrict__ Uh,
                                                float* __restrict__ partials,
                                                const float* __restrict__ params) {
    __shared__ unsigned sm[4096];   // 16 KB
    __shared__ uint4 gl[18];        // layer-0 gates (packed f16)
    __shared__ float wsum[4];
    const int t = threadIdx.x;
    const size_t base = (size_t)blockIdx.x * 4096;
    h2 v[16];
    float ss = 0.f;

    const float4* xs = (const float4*)(src + base + (size_t)t * 16);

    if (t < 36) {
        uint4 g = gate_u4(params + t * 3);
        if (t < 18) gl[t] = g;
        if (blockIdx.x == 0) {
            Uh[t] = g;
            if (t >= 18) Uh[t + 18] = make_uint4(g.w, g.z, g.y, g.x);  // swapped
        }
    }

#pragma unroll
    for (int j = 0; j < 4; j++) {
        float4 q = xs[j];
        v[j * 4 + 0] = (h2){(_Float16)q.x, (_Float16)0.f};
        v[j * 4 + 1] = (h2){(_Float16)q.y, (_Float16)0.f};
        v[j * 4 + 2] = (h2){(_Float16)q.z, (_Float16)0.f};
        v[j * 4 + 3] = (h2){(_Float16)q.w, (_Float16)0.f};
        ss += q.x * q.x + q.y * q.y + q.z * q.z + q.w * q.w;
    }
#pragma unroll
    for (int m = 32; m >= 1; m >>= 1) ss += __shfl_xor(ss, m, 64);
    if ((t & 63) == 0) wsum[t >> 6] = ss;
    __syncthreads();   // gates + wsum visible

    const uint4* Ut = gl;

    // phase 1: bits 0..3
#pragma unroll
    for (int b = 0; b < 4; b++) {
        G4h g = loadg(Ut, b);
#pragma unroll
        for (int k = 0; k < 16; k++)
            if (!(k & (1 << b))) bflyG(v[k], v[k | (1 << b)], g);
    }
    // exchange 1 write: consecutive k -> 4 x b128
#pragma unroll
    for (int j = 0; j < 4; j++)
        *(uint4*)&sm[swz4((t << 4) | (j << 2))] =
            make_uint4(U(v[j * 4]), U(v[j * 4 + 1]), U(v[j * 4 + 2]), U(v[j * 4 + 3]));
    __syncthreads();
    if (t == 0) partials[blockIdx.x] = wsum[0] + wsum[1] + wsum[2] + wsum[3];
#pragma unroll
    for (int k = 0; k < 16; k++)
        v[k] = H(sm[swz4((t & 15) | (k << 4) | ((t >> 4) << 8))]);
    // phase 2: bits 4..7
#pragma unroll
    for (int b = 4; b < 8; b++) {
        G4h g = loadg(Ut, b);
        const int pb = 1 << (b - 4);
#pragma unroll
        for (int k = 0; k < 16; k++)
            if (!(k & pb)) bflyG(v[k], v[k | pb], g);
    }
    // exchange 2: write back own slots (disjoint), read phase-3 layout
#pragma unroll
    for (int k = 0; k < 16; k++)
        sm[swz4((t & 15) | (k << 4) | ((t >> 4) << 8))] = U(v[k]);
    __syncthreads();
#pragma unroll
    for (int k = 0; k < 16; k++)
        v[k] = H(sm[swz4(t | (k << 8))]);
    // phase 3: bits 8..11
#pragma unroll
    for (int b = 8; b < 12; b++) {
        G4h g = loadg(Ut, b);
        const int pb = 1 << (b - 8);
#pragma unroll
        for (int k = 0; k < 16; k++)
            if (!(k & pb)) bflyG(v[k], v[k | pb], g);
    }
    // store, x-order (lane-contiguous per k)
#pragma unroll
    for (int k = 0; k < 16; k++)
        dst[base + (t | (k << 8))] = U(v[k]);
}

// ---- pass 2: layer-0 bits 12..17 + virtual layer-1 gates {16,17,0,13,14,15} ---
// Tile: lows x0..5 (lane) x highs x12..17; mid x6..11 = chunk. Writes u-order.
__global__ __launch_bounds__(256, 8) void pass2(const unsigned* __restrict__ src,
                                                unsigned* __restrict__ dst,
                                                const uint4* __restrict__ Uh) {
    __shared__ unsigned sm[4096];
    const int t = threadIdx.x;
    const unsigned blk = blockIdx.x;
    const unsigned batch = blk >> 6, chunk = blk & 63;
    const size_t bb = (size_t)batch << NW;
    const int lane6 = t & 63, j2 = t >> 6;
    const uint4* Ut0  = Uh;
    const uint4* Ut1  = Uh + 18;
    h2 v[16];

    // load: element k = x12..15, j2 = x16..17
#pragma unroll
    for (int k = 0; k < 16; k++)
        v[k] = H(src[bb + ((size_t)((j2 << 4) | k) << 12) + (chunk << 6) + lane6]);

    // phase 1: layer-0 bits 12..15 on k-bits 0..3
#pragma unroll
    for (int b = 0; b < 4; b++) {
        G4h g = loadg(Ut0, 12 + b);
#pragma unroll
        for (int k = 0; k < 16; k++)
            if (!(k & (1 << b))) bflyG(v[k], v[k | (1 << b)], g);
    }

    // exchange 1: slot L = (x17 x16 x15 x14 x13 x12)<<6 | (x5..x1 x0)
#pragma unroll
    for (int k = 0; k < 16; k++)
        sm[SWZ2((((j2 << 4) | k) << 6) | lane6)] = U(v[k]);
    __syncthreads();
    // phase-2 ownership: elem bits (k0,k1,k2,k3) = (x0,x15,x16,x17); fixed l5=x1..5, m3=x12..14
    const int l5 = t & 31, m3 = t >> 5;
#pragma unroll
    for (int k = 0; k < 16; k++) {
        int L = ((((k >> 3) << 5) | (((k >> 2) & 1) << 4) | (((k >> 1) & 1) << 3) | m3) << 6)
                | (l5 << 1) | (k & 1);
        v[k] = H(sm[SWZ2(L)]);
    }

    // layer-0 bit 16 (elem bit 2), bit 17 (elem bit 3)
    { G4h g = loadg(Ut0, 16);
#pragma unroll
      for (int k = 0; k < 16; k++) if (!(k & 4)) bflyG(v[k], v[k | 4], g); }
    { G4h g = loadg(Ut0, 17);
#pragma unroll
      for (int k = 0; k < 16; k++) if (!(k & 8)) bflyG(v[k], v[k | 8], g); }

    // V16: c={15,16}->^6 ; sel parity = x16^x17 = k2^k3 (compile-time)
    { G4h g = loadg(Ut1, 16);
#pragma unroll
      for (int k = 0; k < 16; k++) if (!(k & 2)) {
          const int q = k ^ 6, pe = ((k >> 2) ^ (k >> 3)) & 1;
          if (pe) bflyG(v[q], v[k], g); else bflyG(v[k], v[q], g);
      } }

    // per-thread parity of x1..x14 for V17 / V0
    const unsigned ptv = (unsigned)((__popc(l5) + __popc((int)chunk) + __popc(m3)) & 1);

    // V17: c={16,17}->^12 ; sel = (k0^k1^k2) ^ ptv
    { G4h gn = loadg(Ut1, 17);
      G4h cA = selg(gn, ptv), cB = selg(gn, ptv ^ 1u);
#pragma unroll
      for (int k = 0; k < 16; k++) if (!(k & 4)) {
          const int q = k ^ 12, pe = (k ^ (k >> 1) ^ (k >> 2)) & 1;
          bflyG(v[k], v[q], pe ? cB : cA);
      } }

    // V0: c={0,16,17}->^13 ; sel = (k0^k1^k2^k3) ^ ptv
    { G4h gn = loadg(Ut1, 0);
      G4h cA = selg(gn, ptv), cB = selg(gn, ptv ^ 1u);
#pragma unroll
      for (int k = 0; k < 16; k++) if (!(k & 1)) {
          const int q = k ^ 13, pe = (k ^ (k >> 1) ^ (k >> 2) ^ (k >> 3)) & 1;
          bflyG(v[k], v[q], pe ? cB : cA);
      } }

    // exchange 2: write back own slots, re-tile to phase-1 ownership
#pragma unroll
    for (int k = 0; k < 16; k++) {
        int L = ((((k >> 3) << 5) | (((k >> 2) & 1) << 4) | (((k >> 1) & 1) << 3) | m3) << 6)
                | (l5 << 1) | (k & 1);
        sm[SWZ2(L)] = U(v[k]);
    }
    __syncthreads();
#pragma unroll
    for (int k = 0; k < 16; k++)
        v[k] = H(sm[SWZ2((((j2 << 4) | k) << 6) | lane6)]);

    // phase 3: V13,V14,V15 on elem bits k=x12..15 ; pt3 = parity(x16,x17) wave-uniform
    const unsigned pt3 = (unsigned)((j2 ^ (j2 >> 1)) & 1);
    const uint4* U3 = Uh + (pt3 ? 36 : 18);
    { G4h g = loadg(U3, 13);   // c={12,13}->^3 ; pe = k1^k2^k3
#pragma unroll
      for (int k = 0; k < 16; k++) if (!(k & 1)) {
          const int q = k ^ 3, pe = ((k >> 1) ^ (k >> 2) ^ (k >> 3)) & 1;
          if (pe) bflyG(v[q], v[k], g); else bflyG(v[k], v[q], g);
      } }
    { G4h g = loadg(U3, 14);   // c={13,14}->^6 ; pe = k2^k3
#pragma unroll
      for (int k = 0; k < 16; k++) if (!(k & 2)) {
          const int q = k ^ 6, pe = ((k >> 2) ^ (k >> 3)) & 1;
          if (pe) bflyG(v[q], v[k], g); else bflyG(v[k], v[q], g);
      } }
    { G4h g = loadg(U3, 15);   // c={14,15}->^12 ; pe = k3
#pragma unroll
      for (int k = 0; k < 16; k++) if (!(k & 4)) {
          const int q = k ^ 12, pe = (k >> 3) & 1;
          if (pe) bflyG(v[q], v[k], g); else bflyG(v[k], v[q], g);
      } }

    // write in u-order: u = prefix-xor(x); gray-walk elem bits x12..15
    const unsigned fixedx = ((unsigned)j2 << 16) | (chunk << 6) | (unsigned)lane6;
    unsigned us = pfx18(fixedx);
#pragma unroll
    for (int i = 0; i < 16; i++) {
        if (i) {
            const int c = ctzc(i);
            us ^= (c == 0) ? 0x3F000u : (c == 1) ? 0x3E000u : (c == 2) ? 0x3C000u : 0x38000u;
        }
        const int s = i ^ (i >> 1);
        dst[bb + us] = U(v[s]);
    }
}

// ---- pass 3: virtual gates j=1..12 = plain butterflies on u-bits 0..11 --------
// u17 (tile-uniform) selects the pre-swapped gate table. Combined scatter
// out[W(u)] = sc*|amp|.
__global__ __launch_bounds__(256, 8) void pass3(const unsigned* __restrict__ src,
                                                float* __restrict__ out,
                                                const uint4* __restrict__ Uh,
                                                const float* __restrict__ partials,
                                                Masks W) {
    __shared__ unsigned sm[4096];
    const int t = threadIdx.x;
    const unsigned blk = blockIdx.x;
    const unsigned batch = blk >> 6, loc = blk & 63;
    const size_t bb = (size_t)batch << NW;
    const size_t base = bb + ((size_t)loc << 12);
    const unsigned u17 = (loc >> 5) & 1;
    const uint4* Ut = Uh + (u17 ? 36 : 18);
    h2 v[16];

    const uint4* xs = (const uint4*)(src + base + (size_t)t * 16);
#pragma unroll
    for (int j = 0; j < 4; j++) {
        uint4 q = xs[j];
        v[j * 4 + 0] = H(q.x);
        v[j * 4 + 1] = H(q.y);
        v[j * 4 + 2] = H(q.z);
        v[j * 4 + 3] = H(q.w);
    }

    // phase 1: u-bits 0..3 -> gates j=1..4
#pragma unroll
    for (int b = 0; b < 4; b++) {
        G4h g = loadg(Ut, b + 1);
#pragma unroll
        for (int k = 0; k < 16; k++)
            if (!(k & (1 << b))) bflyG(v[k], v[k | (1 << b)], g);
    }
#pragma unroll
    for (int j = 0; j < 4; j++)
        *(uint4*)&sm[swz4((t << 4) | (j << 2))] =
            make_uint4(U(v[j * 4]), U(v[j * 4 + 1]), U(v[j * 4 + 2]), U(v[j * 4 + 3]));
    __syncthreads();
#pragma unroll
    for (int k = 0; k < 16; k++)
        v[k] = H(sm[swz4((t & 15) | (k << 4) | ((t >> 4) << 8))]);
    // phase 2: u-bits 4..7 -> gates j=5..8
#pragma unroll
    for (int b = 4; b < 8; b++) {
        G4h g = loadg(Ut, b + 1);
        const int pb = 1 << (b - 4);
#pragma unroll
        for (int k = 0; k < 16; k++)
            if (!(k & pb)) bflyG(v[k], v[k | pb], g);
    }
#pragma unroll
    for (int k = 0; k < 16; k++)
        sm[swz4((t & 15) | (k << 4) | ((t >> 4) << 8))] = U(v[k]);
    __syncthreads();
#pragma unroll
    for (int k = 0; k < 16; k++)
        v[k] = H(sm[swz4(t | (k << 8))]);
    // phase 3: u-bits 8..11 -> gates j=9..12
#pragma unroll
    for (int b = 8; b < 12; b++) {
        G4h g = loadg(Ut, b + 1);
        const int pb = 1 << (b - 8);
#pragma unroll
        for (int k = 0; k < 16; k++)
            if (!(k & pb)) bflyG(v[k], v[k | pb], g);
    }

    // batch norm (exact, from f32 input)
    float nrm = 0.f;
#pragma unroll
    for (int i = 0; i < 64; i++) nrm += partials[batch * 64 + i];
    const float sc = rsqrtf(nrm);

    // scatter: u = loc<<12 | k<<8 | t ; out addr = XOR of W cols over set u-bits
    unsigned f = 0;
    const unsigned fx = (loc << 12) | (unsigned)t;
#pragma unroll
    for (int i = 0; i < 18; i++) {
        if (i >= 8 && i < 12) continue;
        if ((fx >> i) & 1) f ^= W.m[i];
    }
    unsigned fs = f;
#pragma unroll
    for (int i = 0; i < 16; i++) {
        if (i) fs ^= W.m[8 + ctzc(i)];
        const int s = i ^ (i >> 1);
        float re = (float)v[s].x, im = (float)v[s].y;
        out[bb + fs] = sc * sqrtf(fmaf(re, re, im * im));
    }
}

// ---- host: GF(2) machinery ----------------------------------------------------
static unsigned apply_m(const unsigned* col, unsigned x) {
    unsigned r = 0;
    for (int i = 0; i < 18; i++) if ((x >> i) & 1) r ^= col[i];
    return r;
}
static void perm_cols(int l, unsigned* col) {
    for (int i = 0; i < 18; i++) {
        unsigned x = 1u << i;
        for (int g = 0; g < 18; g++) {
            int cb = 17 - ((g + l) % 18), tb = 17 - ((g + l + 1) % 18);
            if ((x >> cb) & 1) x ^= 1u << tb;
        }
        col[i] = x;
    }
}

extern "C" void kernel_launch(void* const* d_in, const int* in_sizes, int n_in,
                              void* d_out, int out_size, void* d_ws, size_t ws_size,
                              hipStream_t stream) {
    const float* x      = (const float*)d_in[0];
    const float* params = (const float*)d_in[1];

    char* ws = (char*)d_ws;
    unsigned* bufA  = (unsigned*)ws;                     // 32 MB
    unsigned* bufB  = (unsigned*)(ws + TOTAL * 4);       // 32 MB
    uint4*    Uh    = (uint4*)(ws + TOTAL * 8);          // 54 * 16 B
    float* partials = (float*)(ws + TOTAL * 8 + 4096);   // 2048 f32

    unsigned P1c[18], P2c[18];
    perm_cols(0, P1c);
    perm_cols(1, P2c);
    Masks W;   // W = P2 * P1 * T^-1 ; Tinv col[k] = {k, k+1}
    for (int k = 0; k < 18; k++) {
        unsigned tinv = (1u << k) | (k < 17 ? (1u << (k + 1)) : 0u);
        W.m[k] = apply_m(P2c, apply_m(P1c, tinv));
    }

    pass1<<<2048, 256, 0, stream>>>(x, bufA, Uh, partials, params);
    pass2<<<2048, 256, 0, stream>>>(bufA, bufB, Uh);
    pass3<<<2048, 256, 0, stream>>>(bufB, (float*)d_out, Uh, partials, W);
}